// Round 5
// baseline (251.042 us; speedup 1.0000x reference)
//
#include <hip/hip_runtime.h>
#include <hip/hip_bf16.h>

typedef __attribute__((ext_vector_type(8))) short bf16x8;
typedef __attribute__((ext_vector_type(4))) float f32x4;

#define DEV static __device__ __forceinline__

DEV unsigned short f2bf(float f) {
    union { float f; unsigned int u; } v; v.f = f;
    return (unsigned short)((v.u + 0x7FFFu + ((v.u >> 16) & 1u)) >> 16);
}
DEV float bf2f(unsigned short s) {
    union { unsigned int u; float f; } v; v.u = ((unsigned int)s) << 16; return v.f;
}
DEV bf16x8 ld_bf8(const unsigned short* p) {
    return *reinterpret_cast<const bf16x8*>(p);
}
DEV f32x4 mfma16(bf16x8 a, bf16x8 b, f32x4 c) {
    return __builtin_amdgcn_mfma_f32_16x16x32_bf16(a, b, c, 0, 0, 0);
}
// 8x8 weight fragment, K padded 8->32, M/N padded 8->16: lane li (lg==0) holds row li.
DEV bf16x8 make_wfrag(const float* wmat, int li, int lg, float scale) {
    bf16x8 f = {};
    if (lg == 0 && li < 8) {
        #pragma unroll
        for (int t = 0; t < 8; t++) f[t] = (short)f2bf(wmat[li*8 + t] * scale);
    }
    return f;
}

// ---------------- K0: f32 -> bf16 convert ----------------
__global__ void k_cvt(const float* __restrict__ s, unsigned short* __restrict__ d, int n) {
    int i = (blockIdx.x * blockDim.x + threadIdx.x) * 4;
    if (i >= n) return;
    float4 v = *reinterpret_cast<const float4*>(s + i);
    ushort4 o = { f2bf(v.x), f2bf(v.y), f2bf(v.z), f2bf(v.w) };
    *reinterpret_cast<ushort4*>(d + i) = o;
}

// ---------------- K1: qkv GEMM + bias + RoPE (r3-validated) ----------------
__global__ __launch_bounds__(256) void k_qkv(
    const unsigned short* __restrict__ xb, const unsigned short* __restrict__ wb,
    const float* __restrict__ bias,
    unsigned short* __restrict__ Qb, unsigned short* __restrict__ Kb,
    unsigned short* __restrict__ Vt)
{
    __shared__ unsigned short As[64][40];
    __shared__ unsigned short Bs[64][40];
    const int m0 = blockIdx.x * 64, c0 = blockIdx.y * 64;
    const int t = threadIdx.x;
    const int w = t >> 6, lane = t & 63, li = lane & 15, lg = lane >> 4;
    const int wr = w >> 1, wc = w & 1;
    f32x4 acc[2][2] = {};
    const int srow = t >> 2, spart = (t & 3) * 8;
    for (int kt = 0; kt < 512; kt += 32) {
        *reinterpret_cast<uint4*>(&As[srow][spart]) =
            *reinterpret_cast<const uint4*>(&xb[(size_t)(m0 + srow) * 512 + kt + spart]);
        *reinterpret_cast<uint4*>(&Bs[srow][spart]) =
            *reinterpret_cast<const uint4*>(&wb[(size_t)(c0 + srow) * 512 + kt + spart]);
        __syncthreads();
        bf16x8 af[2], bfr[2];
        #pragma unroll
        for (int mf = 0; mf < 2; mf++) af[mf] = ld_bf8(&As[wr*32 + mf*16 + li][lg*8]);
        #pragma unroll
        for (int nf = 0; nf < 2; nf++) bfr[nf] = ld_bf8(&Bs[wc*32 + nf*16 + li][lg*8]);
        #pragma unroll
        for (int mf = 0; mf < 2; mf++)
            #pragma unroll
            for (int nf = 0; nf < 2; nf++)
                acc[mf][nf] = mfma16(af[mf], bfr[nf], acc[mf][nf]);
        __syncthreads();
    }
    const int type = c0 >> 9;
    const int head = (c0 & 511) >> 6;
    const float b0 = bias[c0 + wc*32 + li];
    const float b1 = bias[c0 + wc*32 + 16 + li];
    float invf = 0.f;
    if (type < 2) invf = powf(10000.f, -(float)li * (1.f/16.f));
    #pragma unroll
    for (int mf = 0; mf < 2; mf++) {
        #pragma unroll
        for (int r = 0; r < 4; r++) {
            int grow = m0 + wr*32 + mf*16 + lg*4 + r;
            int tok = grow & 2047, bb = grow >> 11;
            float v0 = acc[mf][0][r] + b0;
            float v1 = acc[mf][1][r] + b1;
            if (type < 2) {
                float ang = (wc == 0 ? (float)(tok & 255) : (float)(tok >> 8)) * invf;
                float s, c;
                sincosf(ang, &s, &c);
                float r0 = v0 * c - v1 * s;
                float r1 = v0 * s + v1 * c;
                unsigned short* dst = (type == 0 ? Qb : Kb);
                size_t base = (((size_t)(bb*8 + head)) * 2048 + tok) * 64 + wc*32 + li;
                dst[base]      = f2bf(r0);
                dst[base + 16] = f2bf(r1);
            } else {
                size_t base = (((size_t)(bb*8 + head)) * 64 + wc*32 + li) * 2048 + tok;
                Vt[base]             = f2bf(v0);
                Vt[base + 16 * 2048] = f2bf(v1);
            }
        }
    }
}

// ---------------- K2: pass 1 — l[h][i] = sum_j exp(L'[h,i,j]) ----------------
// grid 512 (XCD-swizzled): virt = [bb | i-tile(7b) | jh]; 8 waves = 8 heads.
__global__ __launch_bounds__(512, 4) void k_lsum(
    const unsigned short* __restrict__ Qb, const unsigned short* __restrict__ Kb,
    const float* __restrict__ w_pre, float* __restrict__ Lp)
{
    __shared__ unsigned short Lt[8192];   // element-major logits [1024 e][8 h]
    const int orig = blockIdx.x;
    const int virt = ((orig & 7) << 6) | (orig >> 3);   // XCD-contiguous
    const int jh = virt & 1, it = (virt >> 1) & 127, bb = virt >> 8;
    const int i0 = it * 16;
    const int tid = threadIdx.x, w = tid >> 6, lane = tid & 63, li = lane & 15, lg = lane >> 4;
    bf16x8 W1f = make_wfrag(w_pre, li, lg, 0.125f * 1.44269504088896340736f);
    const unsigned short* Qp = Qb + (((size_t)(bb*8 + w)) * 2048 + i0 + li) * 64;
    bf16x8 qa0 = ld_bf8(Qp + lg*8), qa1 = ld_bf8(Qp + 32 + lg*8);
    const unsigned short* Kp = Kb + ((size_t)(bb*8 + w)) * 2048 * 64;
    const f32x4 zero = {};
    float lacc0 = 0.f, lacc1 = 0.f;
    #pragma unroll 1
    for (int t = 0; t < 16; t++) {
        const int j0 = jh*1024 + t*64;
        f32x4 sa[4] = {};
        #pragma unroll
        for (int nf = 0; nf < 4; nf++) {
            const unsigned short* kp = Kp + (size_t)(j0 + nf*16 + li) * 64;
            sa[nf] = mfma16(qa0, ld_bf8(kp + lg*8), sa[nf]);
            sa[nf] = mfma16(qa1, ld_bf8(kp + 32 + lg*8), sa[nf]);
        }
        __syncthreads();   // prev iter's premix reads done before overwrite
        #pragma unroll
        for (int nf = 0; nf < 4; nf++)
            #pragma unroll
            for (int r = 0; r < 4; r++)
                Lt[((lg*4 + r)*64 + nf*16 + li)*8 + w] = f2bf(sa[nf][r]);
        __syncthreads();
        #pragma unroll
        for (int x = 0; x < 2; x++) {
            const int i = 2*w + x;
            float s = 0.f;
            #pragma unroll
            for (int jj = 0; jj < 4; jj++) {
                const int e0 = i*64 + jj*16;
                bf16x8 bfv = {};
                if (lg == 0) bfv = *(const bf16x8*)&Lt[(e0 + li)*8];
                f32x4 d = mfma16(bfv, W1f, zero);   // D[e=e0+lg*4+r, g=li]
                s += (exp2f(d[0]) + exp2f(d[1])) + (exp2f(d[2]) + exp2f(d[3]));
            }
            if (x == 0) lacc0 += s; else lacc1 += s;
        }
    }
    lacc0 += __shfl_xor(lacc0, 16); lacc0 += __shfl_xor(lacc0, 32);
    lacc1 += __shfl_xor(lacc1, 16); lacc1 += __shfl_xor(lacc1, 32);
    if (lg == 0 && li < 8) {
        float* Lpw = Lp + (size_t)jh * 32768;
        size_t base = (size_t)bb*2048 + i0;
        Lpw[(base + 2*w + 0)*8 + li] = lacc0;
        Lpw[(base + 2*w + 1)*8 + li] = lacc1;
    }
}

// ---------------- K3: pass 2 — premix+exp+norm+postmix (in-register), PV --------
__global__ __launch_bounds__(512, 4) void k_attn(
    const unsigned short* __restrict__ Qb, const unsigned short* __restrict__ Kb,
    const unsigned short* __restrict__ Vt,
    const float* __restrict__ w_pre, const float* __restrict__ w_post,
    const float* __restrict__ Lp,
    unsigned short* __restrict__ AOp0, unsigned short* __restrict__ AOp1)
{
    __shared__ unsigned short Lt[8192];
    __shared__ unsigned short Ah[8 * 1168];   // [g][16 i x 72] bf16 (16B-aligned strides)
    __shared__ float Llds[128];               // invl[i][h]
    const int orig = blockIdx.x;
    const int virt = ((orig & 7) << 6) | (orig >> 3);
    const int jh = virt & 1, it = (virt >> 1) & 127, bb = virt >> 8;
    const int i0 = it * 16;
    const int tid = threadIdx.x, w = tid >> 6, lane = tid & 63, li = lane & 15, lg = lane >> 4;
    bf16x8 W1f = make_wfrag(w_pre, li, lg, 0.125f * 1.44269504088896340736f);
    bf16x8 W2f = make_wfrag(w_post, li, lg, 1.0f);
    if (tid < 128) {
        size_t g = ((size_t)bb*2048 + i0 + (tid >> 3)) * 8 + (tid & 7);
        Llds[tid] = 1.0f / (Lp[g] + Lp[32768 + g]);
    }
    const unsigned short* Qp = Qb + (((size_t)(bb*8 + w)) * 2048 + i0 + li) * 64;
    bf16x8 qa0 = ld_bf8(Qp + lg*8), qa1 = ld_bf8(Qp + 32 + lg*8);
    const unsigned short* Kp = Kb + ((size_t)(bb*8 + w)) * 2048 * 64;
    const unsigned short* Vp = Vt + ((size_t)(bb*8 + w)) * 64 * 2048;
    __syncthreads();
    const int lgc = lg & 1;
    f32x4 invlA = *(const f32x4*)&Llds[(2*w + 0)*8 + lgc*4];
    f32x4 invlB = *(const f32x4*)&Llds[(2*w + 1)*8 + lgc*4];
    const f32x4 zero = {};
    f32x4 oacc[4] = {};
    #pragma unroll 1
    for (int t = 0; t < 16; t++) {
        const int j0 = jh*1024 + t*64;
        // V prefetch (consumed after 2 barriers in PV)
        bf16x8 vf[8];
        #pragma unroll
        for (int nf = 0; nf < 4; nf++) {
            const unsigned short* vp = Vp + (size_t)(nf*16 + li) * 2048 + j0;
            vf[nf*2]   = ld_bf8(vp + lg*8);
            vf[nf*2+1] = ld_bf8(vp + 32 + lg*8);
        }
        // QK^T
        f32x4 sa[4] = {};
        #pragma unroll
        for (int nf = 0; nf < 4; nf++) {
            const unsigned short* kp = Kp + (size_t)(j0 + nf*16 + li) * 64;
            sa[nf] = mfma16(qa0, ld_bf8(kp + lg*8), sa[nf]);
            sa[nf] = mfma16(qa1, ld_bf8(kp + 32 + lg*8), sa[nf]);
        }
        #pragma unroll
        for (int nf = 0; nf < 4; nf++)
            #pragma unroll
            for (int r = 0; r < 4; r++)
                Lt[((lg*4 + r)*64 + nf*16 + li)*8 + w] = f2bf(sa[nf][r]);
        __syncthreads();
        // fused premix -> exp2*invl -> pack -> shfl -> postmix -> Ah
        #pragma unroll
        for (int x = 0; x < 2; x++) {
            const int i = 2*w + x;
            f32x4 invl = x ? invlB : invlA;
            #pragma unroll
            for (int jj = 0; jj < 4; jj++) {
                const int e0 = i*64 + jj*16;
                bf16x8 bfv = {};
                if (lg == 0) bfv = *(const bf16x8*)&Lt[(e0 + li)*8];
                f32x4 d = mfma16(W1f, bfv, zero);   // D[g=lg*4+r, e=e0+li]
                float p0 = exp2f(d[0]) * invl[0];
                float p1 = exp2f(d[1]) * invl[1];
                float p2 = exp2f(d[2]) * invl[2];
                float p3 = exp2f(d[3]) * invl[3];
                unsigned lo = (unsigned)f2bf(p0) | ((unsigned)f2bf(p1) << 16);
                unsigned hi = (unsigned)f2bf(p2) | ((unsigned)f2bf(p3) << 16);
                unsigned plo = (unsigned)__shfl_xor((int)lo, 16);
                unsigned phi = (unsigned)__shfl_xor((int)hi, 16);
                union { unsigned u[4]; bf16x8 v; } af;
                af.u[0] = lo; af.u[1] = hi; af.u[2] = plo; af.u[3] = phi;
                // lanes lg>=1 carry garbage in k-slices 8..31 -> W2f zero rows
                f32x4 a2 = mfma16(af.v, W2f, zero); // D[e=e0+lg*4+r, g'=li]
                if (li < 8) {
                    ushort4 o = { f2bf(a2[0]), f2bf(a2[1]), f2bf(a2[2]), f2bf(a2[3]) };
                    *(ushort4*)&Ah[li*1168 + i*72 + jj*16 + lg*4] = o;
                }
            }
        }
        __syncthreads();
        // PV (A from Ah, B = prefetched V regs)
        #pragma unroll
        for (int kk = 0; kk < 2; kk++) {
            bf16x8 pa = *(const bf16x8*)&Ah[w*1168 + li*72 + kk*32 + lg*8];
            #pragma unroll
            for (int nf = 0; nf < 4; nf++)
                oacc[nf] = mfma16(pa, vf[nf*2 + kk], oacc[nf]);
        }
    }
    unsigned short* ao = jh ? AOp1 : AOp0;
    #pragma unroll
    for (int nf = 0; nf < 4; nf++)
        #pragma unroll
        for (int r = 0; r < 4; r++)
            ao[((size_t)bb*2048 + i0 + lg*4 + r)*512 + w*64 + nf*16 + li] = f2bf(oacc[nf][r]);
}

// ---------------- K4: output GEMM (sums the two j-half partials) --------
__global__ __launch_bounds__(256) void k_out(
    const unsigned short* __restrict__ a0, const unsigned short* __restrict__ a1,
    const unsigned short* __restrict__ wb, const float* __restrict__ bias,
    float* __restrict__ out)
{
    __shared__ unsigned short As[64][40];
    __shared__ unsigned short Bs[64][40];
    const int m0 = blockIdx.x * 64, c0 = blockIdx.y * 64;
    const int t = threadIdx.x;
    const int w = t >> 6, lane = t & 63, li = lane & 15, lg = lane >> 4;
    const int wr = w >> 1, wc = w & 1;
    f32x4 acc[2][2] = {};
    const int srow = t >> 2, spart = (t & 3) * 8;
    for (int kt = 0; kt < 512; kt += 32) {
        size_t aidx = (size_t)(m0 + srow) * 512 + kt + spart;
        uint4 ua = *(const uint4*)&a0[aidx];
        uint4 ub = *(const uint4*)&a1[aidx];
        const unsigned short* pa = (const unsigned short*)&ua;
        const unsigned short* pb = (const unsigned short*)&ub;
        unsigned short us[8];
        #pragma unroll
        for (int q = 0; q < 8; q++) us[q] = f2bf(bf2f(pa[q]) + bf2f(pb[q]));
        *reinterpret_cast<uint4*>(&As[srow][spart]) = *(const uint4*)us;
        *reinterpret_cast<uint4*>(&Bs[srow][spart]) =
            *reinterpret_cast<const uint4*>(&wb[(size_t)(c0 + srow) * 512 + kt + spart]);
        __syncthreads();
        bf16x8 af[2], bfr[2];
        #pragma unroll
        for (int mf = 0; mf < 2; mf++) af[mf] = ld_bf8(&As[wr*32 + mf*16 + li][lg*8]);
        #pragma unroll
        for (int nf = 0; nf < 2; nf++) bfr[nf] = ld_bf8(&Bs[wc*32 + nf*16 + li][lg*8]);
        #pragma unroll
        for (int mf = 0; mf < 2; mf++)
            #pragma unroll
            for (int nf = 0; nf < 2; nf++)
                acc[mf][nf] = mfma16(af[mf], bfr[nf], acc[mf][nf]);
        __syncthreads();
    }
    #pragma unroll
    for (int mf = 0; mf < 2; mf++)
        #pragma unroll
        for (int nf = 0; nf < 2; nf++)
            #pragma unroll
            for (int r = 0; r < 4; r++) {
                int grow = m0 + wr*32 + mf*16 + lg*4 + r;
                int gcol = c0 + wc*32 + nf*16 + li;
                out[(size_t)grow * 512 + gcol] = acc[mf][nf][r] + bias[gcol];
            }
}

extern "C" void kernel_launch(void* const* d_in, const int* in_sizes, int n_in,
                              void* d_out, int out_size, void* d_ws, size_t ws_size,
                              hipStream_t stream)
{
    const float* x      = (const float*)d_in[0];
    const float* w_qkv  = (const float*)d_in[1];
    const float* b_qkv  = (const float*)d_in[2];
    const float* w_pre  = (const float*)d_in[3];
    const float* w_post = (const float*)d_in[4];
    const float* w_out  = (const float*)d_in[5];
    const float* b_out  = (const float*)d_in[6];
    float* out = (float*)d_out;

    char* ws = (char*)d_ws;
    unsigned short* xb    = (unsigned short*)(ws);              // 4 MB (dead after k_qkv)
    unsigned short* AOp1  = (unsigned short*)(ws);              // overlays xb
    unsigned short* wqkvb = (unsigned short*)(ws + 4194304);    // 1.5 MB
    unsigned short* woutb = (unsigned short*)(ws + 5767168);    // 0.5 MB
    unsigned short* Qb    = (unsigned short*)(ws + 6291456);    // 4 MB
    unsigned short* Kb    = (unsigned short*)(ws + 10485760);   // 4 MB
    unsigned short* Vt    = (unsigned short*)(ws + 14680064);   // 4 MB
    unsigned short* AOp0  = (unsigned short*)(ws + 18874368);   // 4 MB
    float* Lp             = (float*)(ws + 23068672);            // 2 x 128 KB

    k_cvt<<<2048, 256, 0, stream>>>(x, xb, 2097152);
    k_cvt<<<768, 256, 0, stream>>>(w_qkv, wqkvb, 786432);
    k_cvt<<<256, 256, 0, stream>>>(w_out, woutb, 262144);
    k_qkv<<<dim3(64, 24), 256, 0, stream>>>(xb, wqkvb, b_qkv, Qb, Kb, Vt);
    k_lsum<<<512, 512, 0, stream>>>(Qb, Kb, w_pre, Lp);
    k_attn<<<512, 512, 0, stream>>>(Qb, Kb, Vt, w_pre, w_post, Lp, AOp0, AOp1);
    k_out<<<dim3(64, 8), 256, 0, stream>>>(AOp0, AOp1, woutb, b_out, out);
}